// Round 13
// baseline (153.732 us; speedup 1.0000x reference)
//
#include <hip/hip_runtime.h>
#include <hip/hip_bf16.h>
#include <math.h>

// Problem constants
#define B_ROWS 8192
#define N_PTS  16384
#define D_DIM  256

// GEMM tiling
#define BM 128
#define BN 128
#define BK 32
#define KSTEPS (D_DIM / BK)     // 8
#define NSPLIT 8
#define CHUNK  (N_PTS / NSPLIT) // 2048
#define NTILES (CHUNK / BN)     // 16

// Folded constants
#define SCALE_F 144.26950408889634f   // 100 * log2(e)   (logits scaled to log2 domain)
#define LN2_F   0.6931471805599453f
#define LOG2E_F 1.4426950408889634f
#define GN_F    354.2135193f          // -(256/2) * ln(2*pi*0.01)

typedef __attribute__((ext_vector_type(8))) __bf16 bf16x8;
typedef __attribute__((ext_vector_type(4))) float  f32x4;

__device__ __forceinline__ float fexp2(float x) {
#if __has_builtin(__builtin_amdgcn_exp2f)
    return __builtin_amdgcn_exp2f(x);   // flush-to-zero below 2^-126 is exactly what LSE wants
#else
    return exp2f(x);
#endif
}

__device__ __forceinline__ void async_load16(const void* g, void* l) {
    __builtin_amdgcn_global_load_lds(
        (const __attribute__((address_space(1))) void*)g,
        (__attribute__((address_space(3))) void*)l,
        16, 0, 0);
}

// ---- fused prep: ONE launch for x-conv, X-conv, W-lse ----
// block 0: lseW = logsumexp(W). blocks 1..1536: 16 rows each (4 iters x
// 4 waves x 1 row) over the unified row space [x rows 0..8191 | X rows
// 8192..24575]. Grid cut 6145 -> 1537 to probe dispatch-ramp cost.
__global__ void prep_all_kernel(const float* __restrict__ x, const float* __restrict__ X,
                                const float* __restrict__ W,
                                __bf16* __restrict__ xb, __bf16* __restrict__ Xb,
                                float* __restrict__ rc, float* __restrict__ c2,
                                float* __restrict__ lsew)
{
    const int blk = blockIdx.x;
    if (blk == 0) {
        const int t = threadIdx.x;   // 256 threads
        float4 v[16];
        float mx = -INFINITY;
        #pragma unroll
        for (int i = 0; i < 16; ++i) {
            v[i] = ((const float4*)W)[i * 256 + t];
            mx = fmaxf(mx, fmaxf(fmaxf(v[i].x, v[i].y), fmaxf(v[i].z, v[i].w)));
        }
        #pragma unroll
        for (int off = 32; off; off >>= 1) mx = fmaxf(mx, __shfl_xor(mx, off));
        __shared__ float sm[4];
        __shared__ float ss[4];
        if ((t & 63) == 0) sm[t >> 6] = mx;
        __syncthreads();
        const float M = fmaxf(fmaxf(sm[0], sm[1]), fmaxf(sm[2], sm[3]));
        float acc = 0.f;
        #pragma unroll
        for (int i = 0; i < 16; ++i)
            acc += __expf(v[i].x - M) + __expf(v[i].y - M) + __expf(v[i].z - M) + __expf(v[i].w - M);
        #pragma unroll
        for (int off = 32; off; off >>= 1) acc += __shfl_xor(acc, off);
        if ((t & 63) == 0) ss[t >> 6] = acc;
        __syncthreads();
        if (t == 0) lsew[0] = M + __logf(ss[0] + ss[1] + ss[2] + ss[3]);
        return;
    }

    const int lane = threadIdx.x & 63;
    const int wv   = threadIdx.x >> 6;
    #pragma unroll
    for (int it = 0; it < 4; ++it) {
        const int row = (blk - 1) * 16 + it * 4 + wv;
        if (row < B_ROWS) {
            const float4 v = *((const float4*)(x + (size_t)row * D_DIM) + lane);
            union { __bf16 h[4]; ushort4 u; } cv;
            cv.h[0] = (__bf16)v.x; cv.h[1] = (__bf16)v.y;
            cv.h[2] = (__bf16)v.z; cv.h[3] = (__bf16)v.w;
            *((ushort4*)((unsigned short*)xb + (size_t)row * D_DIM) + lane) = cv.u;
            float sq = fmaf(v.x, v.x, fmaf(v.y, v.y, fmaf(v.z, v.z, v.w * v.w)));
            #pragma unroll
            for (int off = 32; off; off >>= 1) sq += __shfl_down(sq, off);
            if (lane == 0) rc[row] = GN_F - 50.0f * sq;
        } else {
            const int r2 = row - B_ROWS;
            const float4 v = *((const float4*)(X + (size_t)r2 * D_DIM) + lane);
            union { __bf16 h[4]; ushort4 u; } cv;
            cv.h[0] = (__bf16)v.x; cv.h[1] = (__bf16)v.y;
            cv.h[2] = (__bf16)v.z; cv.h[3] = (__bf16)v.w;
            *((ushort4*)((unsigned short*)Xb + (size_t)r2 * D_DIM) + lane) = cv.u;
            float sq = fmaf(v.x, v.x, fmaf(v.y, v.y, fmaf(v.z, v.z, v.w * v.w)));
            #pragma unroll
            for (int off = 32; off; off >>= 1) sq += __shfl_down(sq, off);
            if (lane == 0) c2[r2] = (W[r2] - 50.0f * sq) * LOG2E_F;
        }
    }
}

// ---- main: fused bf16 MFMA GEMM + online log2-sum-exp over n-chunk ----
// v14 = v13 (A resident + full swizzle, conflicts 0, 83 us) with the B
// staging converted to a counted-vmcnt single-kt pipeline (T3/T4 minimum):
// consume Bs[kt&1] while stage(kt+2) -> just-freed buffer stays in flight
// across the barriers; waits are compile-time-counted (kt0/1: vmcnt(6)
// allowing {next stage + 4 c2 loads}; kt2-6: vmcnt(2); last step: 0).
// c2 for nt is loaded in nt-1's epilogue, pinned below the kt6/kt7 stage
// issues by an empty memory-clobber asm so the FIFO counts stay exact
// (v4's failure mode). Pre-committed: gemm >= 85 us -> revert to v13.
__global__ __launch_bounds__(256, 2) void kde_gemm(
    const __bf16* __restrict__ xb, const __bf16* __restrict__ Xb,
    const float* __restrict__ c2, float* __restrict__ pm, float* __restrict__ ps)
{
    __shared__ __align__(16) __bf16 Asf[KSTEPS * BM * BK];   // 64 KB, resident
    __shared__ __align__(16) __bf16 Bs[2][BN * BK];          // 2 x 8 KB

    // reduction buffers alias the A panel (dead after the last k-loop barrier)
    float* redM = (float*)Asf;            // [2][BM]
    float* redS = (float*)Asf + 2 * BM;   // [2][BM]

    const int tid  = threadIdx.x;
    const int lane = tid & 63;
    const int w    = tid >> 6;
    const int wy   = w >> 1;
    const int wx   = w & 1;
    const int l15  = lane & 15;
    const int quad = lane >> 4;
    // swizzled 16B-granule column for A AND B reads (verified: conflicts = 0)
    const int qx   = quad ^ ((l15 >> 1) & 3);

    const int b0    = blockIdx.x * BM;
    const int chunk = blockIdx.y;
    const int nbase = chunk * CHUNK;

    // per-lane online LSE state: rows = wy*64 + i*16 + quad*4 + r
    float m_[4][4], s_[4][4];
    #pragma unroll
    for (int i = 0; i < 4; ++i)
        #pragma unroll
        for (int r = 0; r < 4; ++r) { m_[i][r] = -INFINITY; s_[i][r] = 0.0f; }

    // staging geometry (pre-swizzled source granule column)
    const int row0 = tid >> 2;
    const int kcs  = (tid & 3) ^ ((tid >> 3) & 3);
    const int ldsbase0 = (w * 64) * 8;          // elements; wave-uniform
    const int ldsbase1 = (256 + w * 64) * 8;

    const __bf16* XbBase0 = Xb + (size_t)(nbase + row0) * D_DIM + kcs * 8;
    const __bf16* XbBase1 = XbBase0 + (size_t)64 * D_DIM;

    // ---- prologue: A panel (16 loads) + B kt0,kt1 of nt0 (4 loads) ----
    {
        const __bf16* xrow0 = xb + (size_t)(b0 + row0) * D_DIM + kcs * 8;
        const __bf16* xrow1 = xrow0 + (size_t)64 * D_DIM;
        #pragma unroll
        for (int kt = 0; kt < KSTEPS; ++kt) {
            async_load16(xrow0 + kt * BK, &Asf[kt * (BM * BK) + ldsbase0]);
            async_load16(xrow1 + kt * BK, &Asf[kt * (BM * BK) + ldsbase1]);
        }
    }
    async_load16(XbBase0,      &Bs[0][ldsbase0]);
    async_load16(XbBase1,      &Bs[0][ldsbase1]);
    async_load16(XbBase0 + BK, &Bs[1][ldsbase0]);
    async_load16(XbBase1 + BK, &Bs[1][ldsbase1]);
    asm volatile("" ::: "memory");   // pin c2 loads BELOW the stage issues (FIFO order)
    float c2v[4];
    #pragma unroll
    for (int j = 0; j < 4; ++j)
        c2v[j] = c2[nbase + wx * 64 + j * 16 + l15];

    for (int nt = 0; nt < NTILES; ++nt) {
        const int lastNt = (nt == NTILES - 1);

        f32x4 acc[4][4];
        #pragma unroll
        for (int i = 0; i < 4; ++i)
            #pragma unroll
            for (int j = 0; j < 4; ++j) {
                f32x4 z = {0.f, 0.f, 0.f, 0.f};
                acc[i][j] = z;
            }

        #pragma unroll
        for (int kt = 0; kt < KSTEPS; ++kt) {
            // counted wait: stage(kt) landed; newer loads stay in flight.
            // FIFO at kt top: kt0:[s0,s1,c2] kt1:[s1,c2,s2] kt2:[c2,s2,s3]
            // kt>=3:[s_kt,s_kt+1]  (2 loads per stage, 4 per c2 group)
            if (kt <= 1)
                asm volatile("s_waitcnt vmcnt(6)");
            else if (kt == KSTEPS - 1 && lastNt)
                asm volatile("s_waitcnt vmcnt(0)");
            else
                asm volatile("s_waitcnt vmcnt(2)");
            __builtin_amdgcn_s_barrier();   // all waves' stage(kt) portions visible

            bf16x8 af[4], bfr[4];
            #pragma unroll
            for (int i = 0; i < 4; ++i)
                af[i] = *(const bf16x8*)&Asf[kt * (BM * BK)
                                             + (wy * 64 + i * 16 + l15) * BK + qx * 8];
            #pragma unroll
            for (int j = 0; j < 4; ++j)
                bfr[j] = *(const bf16x8*)&Bs[kt & 1][(wx * 64 + j * 16 + l15) * BK + qx * 8];
            #pragma unroll
            for (int i = 0; i < 4; ++i)
                #pragma unroll
                for (int j = 0; j < 4; ++j)
                    acc[i][j] = __builtin_amdgcn_mfma_f32_16x16x32_bf16(af[i], bfr[j], acc[i][j], 0, 0, 0);

            __builtin_amdgcn_s_barrier();   // all waves done reading Bs[kt&1]
            // stage(kt+2) into the just-freed buffer ((kt+2)&1 == kt&1);
            // kt6/kt7 roll into nt+1's kt0/kt1.
            if (!(lastNt && kt >= KSTEPS - 2)) {
                const int ktn = (kt + 2) & (KSTEPS - 1);
                const int ntn = nt + ((kt + 2) >> 3);
                const size_t boff = (size_t)ntn * BN * D_DIM + (size_t)ktn * BK;
                async_load16(XbBase0 + boff, &Bs[kt & 1][ldsbase0]);
                async_load16(XbBase1 + boff, &Bs[kt & 1][ldsbase1]);
            }
        }

        asm volatile("" ::: "memory");   // pin next-nt c2 loads below kt6/kt7 stages

        // fused epilogue: online LSE (log2 domain), purely per-lane
        #pragma unroll
        for (int i = 0; i < 4; ++i) {
            #pragma unroll
            for (int r = 0; r < 4; ++r) {
                float v0 = fmaf(SCALE_F, acc[i][0][r], c2v[0]);
                float v1 = fmaf(SCALE_F, acc[i][1][r], c2v[1]);
                float v2 = fmaf(SCALE_F, acc[i][2][r], c2v[2]);
                float v3 = fmaf(SCALE_F, acc[i][3][r], c2v[3]);
                float tm = fmaxf(fmaxf(v0, v1), fmaxf(v2, v3));
                float om = m_[i][r];
                float nm = fmaxf(om, tm);
                float e  = fexp2(v0 - nm) + fexp2(v1 - nm) + fexp2(v2 - nm) + fexp2(v3 - nm);
                s_[i][r] = fmaf(s_[i][r], fexp2(om - nm), e);
                m_[i][r] = nm;
            }
        }

        // c2 for nt+1 (4 dword loads; counted in the kt0/kt1 waits above)
        if (!lastNt) {
            const int n1 = nbase + (nt + 1) * BN;
            #pragma unroll
            for (int j = 0; j < 4; ++j)
                c2v[j] = c2[n1 + wx * 64 + j * 16 + l15];
        }
    }

    // reduce (m,s) across the 16 lanes sharing each row, then across wx waves.
    // redM/redS alias Asf: all Asf reads completed at the final k-loop barrier.
    #pragma unroll
    for (int i = 0; i < 4; ++i) {
        #pragma unroll
        for (int r = 0; r < 4; ++r) {
            float mm = m_[i][r], ss = s_[i][r];
            #pragma unroll
            for (int off = 1; off < 16; off <<= 1) {
                float om = __shfl_xor(mm, off);
                float os = __shfl_xor(ss, off);
                float nm = fmaxf(mm, om);
                ss = ss * fexp2(mm - nm) + os * fexp2(om - nm);
                mm = nm;
            }
            if (l15 == 0) {
                int row = wy * 64 + i * 16 + quad * 4 + r;
                redM[wx * BM + row] = mm;
                redS[wx * BM + row] = ss;
            }
        }
    }
    __syncthreads();
    if (tid < BM) {
        float m0 = redM[0 * BM + tid], m1 = redM[1 * BM + tid];
        float s0 = redS[0 * BM + tid], s1 = redS[1 * BM + tid];
        float M = fmaxf(m0, m1);
        float S = s0 * fexp2(m0 - M) + s1 * fexp2(m1 - M);
        pm[(size_t)(b0 + tid) * NSPLIT + chunk] = M;
        ps[(size_t)(b0 + tid) * NSPLIT + chunk] = S;
    }
}

// ---- combine partial (m,s) across N-chunks ----
__global__ void kde_combine(const float* __restrict__ pm, const float* __restrict__ ps,
                            const float* __restrict__ rc, const float* __restrict__ lsew,
                            float* __restrict__ out)
{
    int b = blockIdx.x * blockDim.x + threadIdx.x;
    if (b >= B_ROWS) return;
    float M = -INFINITY;
    #pragma unroll
    for (int c = 0; c < NSPLIT; ++c) M = fmaxf(M, pm[(size_t)b * NSPLIT + c]);
    float S = 0.f;
    #pragma unroll
    for (int c = 0; c < NSPLIT; ++c)
        S += ps[(size_t)b * NSPLIT + c] * fexp2(pm[(size_t)b * NSPLIT + c] - M);
    out[b] = (M + log2f(S)) * LN2_F + rc[b] - lsew[0];
}

extern "C" void kernel_launch(void* const* d_in, const int* in_sizes, int n_in,
                              void* d_out, int out_size, void* d_ws, size_t ws_size,
                              hipStream_t stream)
{
    const float* x = (const float*)d_in[0];
    const float* X = (const float*)d_in[1];
    const float* W = (const float*)d_in[2];
    float* out = (float*)d_out;

    char* ws = (char*)d_ws;
    size_t off = 0;
    __bf16* xb = (__bf16*)(ws + off); off += (size_t)B_ROWS * D_DIM * 2;   // 4 MB
    __bf16* Xb = (__bf16*)(ws + off); off += (size_t)N_PTS  * D_DIM * 2;   // 8 MB
    float* rc   = (float*)(ws + off); off += (size_t)B_ROWS * 4;
    float* c2   = (float*)(ws + off); off += (size_t)N_PTS * 4;
    float* lsew = (float*)(ws + off); off += 256;
    float* pm   = (float*)(ws + off); off += (size_t)B_ROWS * NSPLIT * 4;
    float* ps   = (float*)(ws + off); off += (size_t)B_ROWS * NSPLIT * 4;

    const int prep_blocks = 1 + (B_ROWS + N_PTS) / 16;   // 1537
    prep_all_kernel<<<prep_blocks, 256, 0, stream>>>(x, X, W, xb, Xb, rc, c2, lsew);
    kde_gemm<<<dim3(B_ROWS / BM, NSPLIT), 256, 0, stream>>>(xb, Xb, c2, pm, ps);
    kde_combine<<<B_ROWS / 256, 256, 0, stream>>>(pm, ps, rc, lsew, out);
}

// Round 14
// 150.018 us; speedup vs baseline: 1.0248x; 1.0248x over previous
//
#include <hip/hip_runtime.h>
#include <hip/hip_bf16.h>
#include <math.h>

// Problem constants
#define B_ROWS 8192
#define N_PTS  16384
#define D_DIM  256

// GEMM tiling
#define BM 128
#define BN 128
#define BK 32
#define KSTEPS (D_DIM / BK)     // 8
#define NSPLIT 8
#define CHUNK  (N_PTS / NSPLIT) // 2048
#define NTILES (CHUNK / BN)     // 16
#define GRIDX  (B_ROWS / BM)    // 64

// Folded constants
#define SCALE_F 144.26950408889634f   // 100 * log2(e)   (logits scaled to log2 domain)
#define LN2_F   0.6931471805599453f
#define LOG2E_F 1.4426950408889634f
#define GN_F    354.2135193f          // -(256/2) * ln(2*pi*0.01)

typedef __attribute__((ext_vector_type(8))) __bf16 bf16x8;
typedef __attribute__((ext_vector_type(4))) float  f32x4;

__device__ __forceinline__ float fexp2(float x) {
#if __has_builtin(__builtin_amdgcn_exp2f)
    return __builtin_amdgcn_exp2f(x);   // flush-to-zero below 2^-126 is exactly what LSE wants
#else
    return exp2f(x);
#endif
}

__device__ __forceinline__ void async_load16(const void* g, void* l) {
    __builtin_amdgcn_global_load_lds(
        (const __attribute__((address_space(1))) void*)g,
        (__attribute__((address_space(3))) void*)l,
        16, 0, 0);
}

// ---- fused prep: ONE launch for x-conv, X-conv, W-lse ----
// block 0:            lseW = logsumexp(W)
// blocks 1..2048:     x -> bf16, rc[b] = GN - 50*||x_b||^2      (4 rows/block)
// blocks 2049..6144:  X -> bf16, c2[n] = (W-50*||X_n||^2)*log2e (4 rows/block)
__global__ void prep_all_kernel(const float* __restrict__ x, const float* __restrict__ X,
                                const float* __restrict__ W,
                                __bf16* __restrict__ xb, __bf16* __restrict__ Xb,
                                float* __restrict__ rc, float* __restrict__ c2,
                                float* __restrict__ lsew)
{
    const int blk = blockIdx.x;
    if (blk == 0) {
        const int t = threadIdx.x;   // 256 threads
        float4 v[16];
        float mx = -INFINITY;
        #pragma unroll
        for (int i = 0; i < 16; ++i) {
            v[i] = ((const float4*)W)[i * 256 + t];
            mx = fmaxf(mx, fmaxf(fmaxf(v[i].x, v[i].y), fmaxf(v[i].z, v[i].w)));
        }
        #pragma unroll
        for (int off = 32; off; off >>= 1) mx = fmaxf(mx, __shfl_xor(mx, off));
        __shared__ float sm[4];
        __shared__ float ss[4];
        if ((t & 63) == 0) sm[t >> 6] = mx;
        __syncthreads();
        const float M = fmaxf(fmaxf(sm[0], sm[1]), fmaxf(sm[2], sm[3]));
        float acc = 0.f;
        #pragma unroll
        for (int i = 0; i < 16; ++i)
            acc += __expf(v[i].x - M) + __expf(v[i].y - M) + __expf(v[i].z - M) + __expf(v[i].w - M);
        #pragma unroll
        for (int off = 32; off; off >>= 1) acc += __shfl_xor(acc, off);
        if ((t & 63) == 0) ss[t >> 6] = acc;
        __syncthreads();
        if (t == 0) lsew[0] = M + __logf(ss[0] + ss[1] + ss[2] + ss[3]);
        return;
    }

    const int lane = threadIdx.x & 63;
    const int wv   = threadIdx.x >> 6;
    if (blk <= B_ROWS / 4) {
        const int row = (blk - 1) * 4 + wv;
        const float4 v = *((const float4*)(x + (size_t)row * D_DIM) + lane);
        union { __bf16 h[4]; ushort4 u; } cv;
        cv.h[0] = (__bf16)v.x; cv.h[1] = (__bf16)v.y;
        cv.h[2] = (__bf16)v.z; cv.h[3] = (__bf16)v.w;
        *((ushort4*)((unsigned short*)xb + (size_t)row * D_DIM) + lane) = cv.u;
        float sq = fmaf(v.x, v.x, fmaf(v.y, v.y, fmaf(v.z, v.z, v.w * v.w)));
        #pragma unroll
        for (int off = 32; off; off >>= 1) sq += __shfl_down(sq, off);
        if (lane == 0) rc[row] = GN_F - 50.0f * sq;
    } else {
        const int row = (blk - (B_ROWS / 4 + 1)) * 4 + wv;
        const float4 v = *((const float4*)(X + (size_t)row * D_DIM) + lane);
        union { __bf16 h[4]; ushort4 u; } cv;
        cv.h[0] = (__bf16)v.x; cv.h[1] = (__bf16)v.y;
        cv.h[2] = (__bf16)v.z; cv.h[3] = (__bf16)v.w;
        *((ushort4*)((unsigned short*)Xb + (size_t)row * D_DIM) + lane) = cv.u;
        float sq = fmaf(v.x, v.x, fmaf(v.y, v.y, fmaf(v.z, v.z, v.w * v.w)));
        #pragma unroll
        for (int off = 32; off; off >>= 1) sq += __shfl_down(sq, off);
        if (lane == 0) c2[row] = (W[row] - 50.0f * sq) * LOG2E_F;
    }
}

// ---- main: fused bf16 MFMA GEMM + online log2-sum-exp over n-chunk ----
// v15 = v13 (champion: gemm 83 us, A resident + full swizzle, conflicts 0,
// Bs[2] pair-staged, separate combine) with ONE change: XCD-aware block
// mapping. Grid 512 = 8 XCDs x 64 blocks exactly; with chunk = bid & 7 the
// round-robin dispatch puts all 64 blocks of chunk k on XCD k, so each
// XCD's 4 MB L2 holds ONE hot 1 MB B-panel instead of thrashing all 8
// (8 MB B + 4 MB A). Lowers the latency of the exposed B-stage drains
// (v14 proved they can't be hidden; so we shorten them instead).
// Pre-committed: gemm within noise -> keep; > 85 us -> revert to v13.
__global__ __launch_bounds__(256, 2) void kde_gemm(
    const __bf16* __restrict__ xb, const __bf16* __restrict__ Xb,
    const float* __restrict__ c2, float* __restrict__ pm, float* __restrict__ ps)
{
    __shared__ __align__(16) __bf16 Asf[KSTEPS * BM * BK];   // 64 KB, resident
    __shared__ __align__(16) __bf16 Bs[2][BN * BK];          // 2 x 8 KB

    // reduction buffers alias the A panel (dead after the last k-loop barrier)
    float* redM = (float*)Asf;            // [2][BM]
    float* redS = (float*)Asf + 2 * BM;   // [2][BM]

    const int tid  = threadIdx.x;
    const int lane = tid & 63;
    const int w    = tid >> 6;
    const int wy   = w >> 1;
    const int wx   = w & 1;
    const int l15  = lane & 15;
    const int quad = lane >> 4;
    // swizzled 16B-granule column for A AND B reads (verified: conflicts = 0)
    const int qx   = quad ^ ((l15 >> 1) & 3);

    // XCD-aware mapping: block i -> XCD i%8 (round-robin dispatch), so
    // chunk = i&7 pins each B-panel to one XCD's L2.
    const int bid   = blockIdx.x;
    const int chunk = bid & 7;            // NSPLIT == 8
    const int b0    = (bid >> 3) * BM;
    const int nbase = chunk * CHUNK;

    // per-lane online LSE state: rows = wy*64 + i*16 + quad*4 + r
    float m_[4][4], s_[4][4];
    #pragma unroll
    for (int i = 0; i < 4; ++i)
        #pragma unroll
        for (int r = 0; r < 4; ++r) { m_[i][r] = -INFINITY; s_[i][r] = 0.0f; }

    // staging pattern: idx = q*256 + tid; row = idx>>2 (64B per row), kc = idx&3.
    // Source granule column pre-swizzled: kcs = kc ^ ((row>>1)&3); identical
    // expression for row and row+64.
    const int row0 = tid >> 2;
    const int kcs  = (tid & 3) ^ ((tid >> 3) & 3);
    const int ldsbase0 = (w * 64) * 8;          // elements; wave-uniform
    const int ldsbase1 = (256 + w * 64) * 8;

    // ---- prologue: stage the ENTIRE A-panel once, source pre-swizzled ----
    {
        const __bf16* xrow0 = xb + (size_t)(b0 + row0) * D_DIM + kcs * 8;
        const __bf16* xrow1 = xrow0 + (size_t)64 * D_DIM;
        #pragma unroll
        for (int kt = 0; kt < KSTEPS; ++kt) {
            async_load16(xrow0 + kt * BK, &Asf[kt * (BM * BK) + ldsbase0]);
            async_load16(xrow1 + kt * BK, &Asf[kt * (BM * BK) + ldsbase1]);
        }
    }

    for (int nt = 0; nt < NTILES; ++nt) {
        const int n0 = nbase + nt * BN;

        float c2v[4];
        #pragma unroll
        for (int j = 0; j < 4; ++j)
            c2v[j] = c2[n0 + wx * 64 + j * 16 + l15];

        f32x4 acc[4][4];
        #pragma unroll
        for (int i = 0; i < 4; ++i)
            #pragma unroll
            for (int j = 0; j < 4; ++j) {
                f32x4 z = {0.f, 0.f, 0.f, 0.f};
                acc[i][j] = z;
            }

        // B staging source pre-swizzled, same kcs as A
        const __bf16* Xrow0 = Xb + (size_t)(n0 + row0) * D_DIM + kcs * 8;
        const __bf16* Xrow1 = Xrow0 + (size_t)64 * D_DIM;

        #pragma unroll
        for (int kk = 0; kk < KSTEPS / 2; ++kk) {
            const int k0 = 2 * kk, k1 = 2 * kk + 1;
            async_load16(Xrow0 + k0 * BK, &Bs[0][ldsbase0]);
            async_load16(Xrow1 + k0 * BK, &Bs[0][ldsbase1]);
            async_load16(Xrow0 + k1 * BK, &Bs[1][ldsbase0]);
            async_load16(Xrow1 + k1 * BK, &Bs[1][ldsbase1]);
            __syncthreads();   // drains vmcnt -> both B tiles (and, first iter, A panel) visible

            #pragma unroll
            for (int p = 0; p < 2; ++p) {
                const int kt = 2 * kk + p;
                bf16x8 af[4], bfr[4];
                #pragma unroll
                for (int i = 0; i < 4; ++i)
                    af[i] = *(const bf16x8*)&Asf[kt * (BM * BK)
                                                 + (wy * 64 + i * 16 + l15) * BK + qx * 8];
                #pragma unroll
                for (int j = 0; j < 4; ++j)
                    bfr[j] = *(const bf16x8*)&Bs[p][(wx * 64 + j * 16 + l15) * BK + qx * 8];
                #pragma unroll
                for (int i = 0; i < 4; ++i)
                    #pragma unroll
                    for (int j = 0; j < 4; ++j)
                        acc[i][j] = __builtin_amdgcn_mfma_f32_16x16x32_bf16(af[i], bfr[j], acc[i][j], 0, 0, 0);
            }
            __syncthreads();   // before next double-step overwrites Bs
        }

        // fused epilogue: online LSE (log2 domain), purely per-lane
        #pragma unroll
        for (int i = 0; i < 4; ++i) {
            #pragma unroll
            for (int r = 0; r < 4; ++r) {
                float v0 = fmaf(SCALE_F, acc[i][0][r], c2v[0]);
                float v1 = fmaf(SCALE_F, acc[i][1][r], c2v[1]);
                float v2 = fmaf(SCALE_F, acc[i][2][r], c2v[2]);
                float v3 = fmaf(SCALE_F, acc[i][3][r], c2v[3]);
                float tm = fmaxf(fmaxf(v0, v1), fmaxf(v2, v3));
                float om = m_[i][r];
                float nm = fmaxf(om, tm);
                float e  = fexp2(v0 - nm) + fexp2(v1 - nm) + fexp2(v2 - nm) + fexp2(v3 - nm);
                s_[i][r] = fmaf(s_[i][r], fexp2(om - nm), e);
                m_[i][r] = nm;
            }
        }
    }

    // reduce (m,s) across the 16 lanes sharing each row, then across wx waves.
    // redM/redS live in the Asf region: all Asf reads completed at the final
    // k-loop barrier, so the aliasing is race-free.
    #pragma unroll
    for (int i = 0; i < 4; ++i) {
        #pragma unroll
        for (int r = 0; r < 4; ++r) {
            float mm = m_[i][r], ss = s_[i][r];
            #pragma unroll
            for (int off = 1; off < 16; off <<= 1) {
                float om = __shfl_xor(mm, off);
                float os = __shfl_xor(ss, off);
                float nm = fmaxf(mm, om);
                ss = ss * fexp2(mm - nm) + os * fexp2(om - nm);
                mm = nm;
            }
            if (l15 == 0) {
                int row = wy * 64 + i * 16 + quad * 4 + r;
                redM[wx * BM + row] = mm;
                redS[wx * BM + row] = ss;
            }
        }
    }
    __syncthreads();
    if (tid < BM) {
        float m0 = redM[0 * BM + tid], m1 = redM[1 * BM + tid];
        float s0 = redS[0 * BM + tid], s1 = redS[1 * BM + tid];
        float M = fmaxf(m0, m1);
        float S = s0 * fexp2(m0 - M) + s1 * fexp2(m1 - M);
        pm[(size_t)(b0 + tid) * NSPLIT + chunk] = M;
        ps[(size_t)(b0 + tid) * NSPLIT + chunk] = S;
    }
}

// ---- combine partial (m,s) across N-chunks ----
__global__ void kde_combine(const float* __restrict__ pm, const float* __restrict__ ps,
                            const float* __restrict__ rc, const float* __restrict__ lsew,
                            float* __restrict__ out)
{
    int b = blockIdx.x * blockDim.x + threadIdx.x;
    if (b >= B_ROWS) return;
    float M = -INFINITY;
    #pragma unroll
    for (int c = 0; c < NSPLIT; ++c) M = fmaxf(M, pm[(size_t)b * NSPLIT + c]);
    float S = 0.f;
    #pragma unroll
    for (int c = 0; c < NSPLIT; ++c)
        S += ps[(size_t)b * NSPLIT + c] * fexp2(pm[(size_t)b * NSPLIT + c] - M);
    out[b] = (M + log2f(S)) * LN2_F + rc[b] - lsew[0];
}

extern "C" void kernel_launch(void* const* d_in, const int* in_sizes, int n_in,
                              void* d_out, int out_size, void* d_ws, size_t ws_size,
                              hipStream_t stream)
{
    const float* x = (const float*)d_in[0];
    const float* X = (const float*)d_in[1];
    const float* W = (const float*)d_in[2];
    float* out = (float*)d_out;

    char* ws = (char*)d_ws;
    size_t off = 0;
    __bf16* xb = (__bf16*)(ws + off); off += (size_t)B_ROWS * D_DIM * 2;   // 4 MB
    __bf16* Xb = (__bf16*)(ws + off); off += (size_t)N_PTS  * D_DIM * 2;   // 8 MB
    float* rc   = (float*)(ws + off); off += (size_t)B_ROWS * 4;
    float* c2   = (float*)(ws + off); off += (size_t)N_PTS * 4;
    float* lsew = (float*)(ws + off); off += 256;
    float* pm   = (float*)(ws + off); off += (size_t)B_ROWS * NSPLIT * 4;
    float* ps   = (float*)(ws + off); off += (size_t)B_ROWS * NSPLIT * 4;

    const int prep_blocks = 1 + B_ROWS / 4 + N_PTS / 4;   // 6145
    prep_all_kernel<<<prep_blocks, 256, 0, stream>>>(x, X, W, xb, Xb, rc, c2, lsew);
    kde_gemm<<<GRIDX * NSPLIT, 256, 0, stream>>>(xb, Xb, c2, pm, ps);
    kde_combine<<<B_ROWS / 256, 256, 0, stream>>>(pm, ps, rc, lsew, out);
}

// Round 15
// 146.565 us; speedup vs baseline: 1.0489x; 1.0236x over previous
//
#include <hip/hip_runtime.h>
#include <hip/hip_bf16.h>
#include <math.h>

// Problem constants
#define B_ROWS 8192
#define N_PTS  16384
#define D_DIM  256

// GEMM tiling
#define BM 128
#define BN 128
#define BK 32
#define KSTEPS (D_DIM / BK)     // 8
#define NSPLIT 8
#define CHUNK  (N_PTS / NSPLIT) // 2048
#define NTILES (CHUNK / BN)     // 16

// Folded constants
#define SCALE_F 144.26950408889634f   // 100 * log2(e)   (logits scaled to log2 domain)
#define LN2_F   0.6931471805599453f
#define LOG2E_F 1.4426950408889634f
#define GN_F    354.2135193f          // -(256/2) * ln(2*pi*0.01)

typedef __attribute__((ext_vector_type(8))) __bf16 bf16x8;
typedef __attribute__((ext_vector_type(4))) float  f32x4;

__device__ __forceinline__ float fexp2(float x) {
#if __has_builtin(__builtin_amdgcn_exp2f)
    return __builtin_amdgcn_exp2f(x);   // flush-to-zero below 2^-126 is exactly what LSE wants
#else
    return exp2f(x);
#endif
}

__device__ __forceinline__ void async_load16(const void* g, void* l) {
    __builtin_amdgcn_global_load_lds(
        (const __attribute__((address_space(1))) void*)g,
        (__attribute__((address_space(3))) void*)l,
        16, 0, 0);
}

// ---- fused prep: ONE launch for x-conv, X-conv, W-lse ----
// block 0:            lseW = logsumexp(W)
// blocks 1..2048:     x -> bf16, rc[b] = GN - 50*||x_b||^2      (4 rows/block)
// blocks 2049..6144:  X -> bf16, c2[n] = (W-50*||X_n||^2)*log2e (4 rows/block)
__global__ void prep_all_kernel(const float* __restrict__ x, const float* __restrict__ X,
                                const float* __restrict__ W,
                                __bf16* __restrict__ xb, __bf16* __restrict__ Xb,
                                float* __restrict__ rc, float* __restrict__ c2,
                                float* __restrict__ lsew)
{
    const int blk = blockIdx.x;
    if (blk == 0) {
        const int t = threadIdx.x;   // 256 threads
        float4 v[16];
        float mx = -INFINITY;
        #pragma unroll
        for (int i = 0; i < 16; ++i) {
            v[i] = ((const float4*)W)[i * 256 + t];
            mx = fmaxf(mx, fmaxf(fmaxf(v[i].x, v[i].y), fmaxf(v[i].z, v[i].w)));
        }
        #pragma unroll
        for (int off = 32; off; off >>= 1) mx = fmaxf(mx, __shfl_xor(mx, off));
        __shared__ float sm[4];
        __shared__ float ss[4];
        if ((t & 63) == 0) sm[t >> 6] = mx;
        __syncthreads();
        const float M = fmaxf(fmaxf(sm[0], sm[1]), fmaxf(sm[2], sm[3]));
        float acc = 0.f;
        #pragma unroll
        for (int i = 0; i < 16; ++i)
            acc += __expf(v[i].x - M) + __expf(v[i].y - M) + __expf(v[i].z - M) + __expf(v[i].w - M);
        #pragma unroll
        for (int off = 32; off; off >>= 1) acc += __shfl_xor(acc, off);
        if ((t & 63) == 0) ss[t >> 6] = acc;
        __syncthreads();
        if (t == 0) lsew[0] = M + __logf(ss[0] + ss[1] + ss[2] + ss[3]);
        return;
    }

    const int lane = threadIdx.x & 63;
    const int wv   = threadIdx.x >> 6;
    if (blk <= B_ROWS / 4) {
        const int row = (blk - 1) * 4 + wv;
        const float4 v = *((const float4*)(x + (size_t)row * D_DIM) + lane);
        union { __bf16 h[4]; ushort4 u; } cv;
        cv.h[0] = (__bf16)v.x; cv.h[1] = (__bf16)v.y;
        cv.h[2] = (__bf16)v.z; cv.h[3] = (__bf16)v.w;
        *((ushort4*)((unsigned short*)xb + (size_t)row * D_DIM) + lane) = cv.u;
        float sq = fmaf(v.x, v.x, fmaf(v.y, v.y, fmaf(v.z, v.z, v.w * v.w)));
        #pragma unroll
        for (int off = 32; off; off >>= 1) sq += __shfl_down(sq, off);
        if (lane == 0) rc[row] = GN_F - 50.0f * sq;
    } else {
        const int row = (blk - (B_ROWS / 4 + 1)) * 4 + wv;
        const float4 v = *((const float4*)(X + (size_t)row * D_DIM) + lane);
        union { __bf16 h[4]; ushort4 u; } cv;
        cv.h[0] = (__bf16)v.x; cv.h[1] = (__bf16)v.y;
        cv.h[2] = (__bf16)v.z; cv.h[3] = (__bf16)v.w;
        *((ushort4*)((unsigned short*)Xb + (size_t)row * D_DIM) + lane) = cv.u;
        float sq = fmaf(v.x, v.x, fmaf(v.y, v.y, fmaf(v.z, v.z, v.w * v.w)));
        #pragma unroll
        for (int off = 32; off; off >>= 1) sq += __shfl_down(sq, off);
        if (lane == 0) c2[row] = (W[row] - 50.0f * sq) * LOG2E_F;
    }
}

// ---- main: fused bf16 MFMA GEMM + online log2-sum-exp over n-chunk ----
// FINAL (== v13, the measured champion: gemm ~83 us, total ~147 us).
// Verified structure: A-panel (64 KB, all 8 k-tiles) staged ONCE with
// pre-swizzled source; B pair-staged into Bs[2] (2 barriers / 2 k-steps);
// both A and B reads use the XOR granule swizzle -> SQ_LDS_BANK_CONFLICT=0;
// redM/redS alias Asf to hold 80 KB exact (2 blocks/CU).
// Refuted alternatives (measured): >2 blocks/CU (reg granularity -> spill),
// reg-cached A/B (spill), counted-vmcnt pipelines (barrier cost >= latency
// saved), fused split-K combine (+30 us cross-XCD fences), XCD chunk
// pinning (FETCH halves, time doesn't -> L2-latency-bound).
__global__ __launch_bounds__(256, 2) void kde_gemm(
    const __bf16* __restrict__ xb, const __bf16* __restrict__ Xb,
    const float* __restrict__ c2, float* __restrict__ pm, float* __restrict__ ps)
{
    __shared__ __align__(16) __bf16 Asf[KSTEPS * BM * BK];   // 64 KB, resident
    __shared__ __align__(16) __bf16 Bs[2][BN * BK];          // 2 x 8 KB

    // reduction buffers alias the A panel (dead after the last k-loop barrier)
    float* redM = (float*)Asf;            // [2][BM]
    float* redS = (float*)Asf + 2 * BM;   // [2][BM]

    const int tid  = threadIdx.x;
    const int lane = tid & 63;
    const int w    = tid >> 6;
    const int wy   = w >> 1;
    const int wx   = w & 1;
    const int l15  = lane & 15;
    const int quad = lane >> 4;
    // swizzled 16B-granule column for A AND B reads (verified: conflicts = 0)
    const int qx   = quad ^ ((l15 >> 1) & 3);

    const int b0    = blockIdx.x * BM;
    const int chunk = blockIdx.y;
    const int nbase = chunk * CHUNK;

    // per-lane online LSE state: rows = wy*64 + i*16 + quad*4 + r
    float m_[4][4], s_[4][4];
    #pragma unroll
    for (int i = 0; i < 4; ++i)
        #pragma unroll
        for (int r = 0; r < 4; ++r) { m_[i][r] = -INFINITY; s_[i][r] = 0.0f; }

    // staging pattern: idx = q*256 + tid; row = idx>>2 (64B per row), kc = idx&3.
    // Source granule column pre-swizzled: kcs = kc ^ ((row>>1)&3); the
    // expression is identical for row and row+64 (bit 1 of row unchanged).
    const int row0 = tid >> 2;
    const int kcs  = (tid & 3) ^ ((tid >> 3) & 3);
    const int ldsbase0 = (w * 64) * 8;          // elements; wave-uniform
    const int ldsbase1 = (256 + w * 64) * 8;

    // ---- prologue: stage the ENTIRE A-panel once, source pre-swizzled ----
    {
        const __bf16* xrow0 = xb + (size_t)(b0 + row0) * D_DIM + kcs * 8;
        const __bf16* xrow1 = xrow0 + (size_t)64 * D_DIM;
        #pragma unroll
        for (int kt = 0; kt < KSTEPS; ++kt) {
            async_load16(xrow0 + kt * BK, &Asf[kt * (BM * BK) + ldsbase0]);
            async_load16(xrow1 + kt * BK, &Asf[kt * (BM * BK) + ldsbase1]);
        }
    }

    for (int nt = 0; nt < NTILES; ++nt) {
        const int n0 = nbase + nt * BN;

        float c2v[4];
        #pragma unroll
        for (int j = 0; j < 4; ++j)
            c2v[j] = c2[n0 + wx * 64 + j * 16 + l15];

        f32x4 acc[4][4];
        #pragma unroll
        for (int i = 0; i < 4; ++i)
            #pragma unroll
            for (int j = 0; j < 4; ++j) {
                f32x4 z = {0.f, 0.f, 0.f, 0.f};
                acc[i][j] = z;
            }

        // B staging source pre-swizzled, same kcs as A
        const __bf16* Xrow0 = Xb + (size_t)(n0 + row0) * D_DIM + kcs * 8;
        const __bf16* Xrow1 = Xrow0 + (size_t)64 * D_DIM;

        #pragma unroll
        for (int kk = 0; kk < KSTEPS / 2; ++kk) {
            const int k0 = 2 * kk, k1 = 2 * kk + 1;
            async_load16(Xrow0 + k0 * BK, &Bs[0][ldsbase0]);
            async_load16(Xrow1 + k0 * BK, &Bs[0][ldsbase1]);
            async_load16(Xrow0 + k1 * BK, &Bs[1][ldsbase0]);
            async_load16(Xrow1 + k1 * BK, &Bs[1][ldsbase1]);
            __syncthreads();   // drains vmcnt -> both B tiles (and, first iter, A panel) visible

            #pragma unroll
            for (int p = 0; p < 2; ++p) {
                const int kt = 2 * kk + p;
                bf16x8 af[4], bfr[4];
                #pragma unroll
                for (int i = 0; i < 4; ++i)
                    af[i] = *(const bf16x8*)&Asf[kt * (BM * BK)
                                                 + (wy * 64 + i * 16 + l15) * BK + qx * 8];
                #pragma unroll
                for (int j = 0; j < 4; ++j)
                    bfr[j] = *(const bf16x8*)&Bs[p][(wx * 64 + j * 16 + l15) * BK + qx * 8];
                #pragma unroll
                for (int i = 0; i < 4; ++i)
                    #pragma unroll
                    for (int j = 0; j < 4; ++j)
                        acc[i][j] = __builtin_amdgcn_mfma_f32_16x16x32_bf16(af[i], bfr[j], acc[i][j], 0, 0, 0);
            }
            __syncthreads();   // before next double-step overwrites Bs
        }

        // fused epilogue: online LSE (log2 domain), purely per-lane
        #pragma unroll
        for (int i = 0; i < 4; ++i) {
            #pragma unroll
            for (int r = 0; r < 4; ++r) {
                float v0 = fmaf(SCALE_F, acc[i][0][r], c2v[0]);
                float v1 = fmaf(SCALE_F, acc[i][1][r], c2v[1]);
                float v2 = fmaf(SCALE_F, acc[i][2][r], c2v[2]);
                float v3 = fmaf(SCALE_F, acc[i][3][r], c2v[3]);
                float tm = fmaxf(fmaxf(v0, v1), fmaxf(v2, v3));
                float om = m_[i][r];
                float nm = fmaxf(om, tm);
                float e  = fexp2(v0 - nm) + fexp2(v1 - nm) + fexp2(v2 - nm) + fexp2(v3 - nm);
                s_[i][r] = fmaf(s_[i][r], fexp2(om - nm), e);
                m_[i][r] = nm;
            }
        }
    }

    // reduce (m,s) across the 16 lanes sharing each row, then across wx waves.
    // redM/redS live in the Asf region: all Asf reads completed at the final
    // k-loop barrier, so the aliasing is race-free.
    #pragma unroll
    for (int i = 0; i < 4; ++i) {
        #pragma unroll
        for (int r = 0; r < 4; ++r) {
            float mm = m_[i][r], ss = s_[i][r];
            #pragma unroll
            for (int off = 1; off < 16; off <<= 1) {
                float om = __shfl_xor(mm, off);
                float os = __shfl_xor(ss, off);
                float nm = fmaxf(mm, om);
                ss = ss * fexp2(mm - nm) + os * fexp2(om - nm);
                mm = nm;
            }
            if (l15 == 0) {
                int row = wy * 64 + i * 16 + quad * 4 + r;
                redM[wx * BM + row] = mm;
                redS[wx * BM + row] = ss;
            }
        }
    }
    __syncthreads();
    if (tid < BM) {
        float m0 = redM[0 * BM + tid], m1 = redM[1 * BM + tid];
        float s0 = redS[0 * BM + tid], s1 = redS[1 * BM + tid];
        float M = fmaxf(m0, m1);
        float S = s0 * fexp2(m0 - M) + s1 * fexp2(m1 - M);
        pm[(size_t)(b0 + tid) * NSPLIT + chunk] = M;
        ps[(size_t)(b0 + tid) * NSPLIT + chunk] = S;
    }
}

// ---- combine partial (m,s) across N-chunks ----
__global__ void kde_combine(const float* __restrict__ pm, const float* __restrict__ ps,
                            const float* __restrict__ rc, const float* __restrict__ lsew,
                            float* __restrict__ out)
{
    int b = blockIdx.x * blockDim.x + threadIdx.x;
    if (b >= B_ROWS) return;
    float M = -INFINITY;
    #pragma unroll
    for (int c = 0; c < NSPLIT; ++c) M = fmaxf(M, pm[(size_t)b * NSPLIT + c]);
    float S = 0.f;
    #pragma unroll
    for (int c = 0; c < NSPLIT; ++c)
        S += ps[(size_t)b * NSPLIT + c] * fexp2(pm[(size_t)b * NSPLIT + c] - M);
    out[b] = (M + log2f(S)) * LN2_F + rc[b] - lsew[0];
}

extern "C" void kernel_launch(void* const* d_in, const int* in_sizes, int n_in,
                              void* d_out, int out_size, void* d_ws, size_t ws_size,
                              hipStream_t stream)
{
    const float* x = (const float*)d_in[0];
    const float* X = (const float*)d_in[1];
    const float* W = (const float*)d_in[2];
    float* out = (float*)d_out;

    char* ws = (char*)d_ws;
    size_t off = 0;
    __bf16* xb = (__bf16*)(ws + off); off += (size_t)B_ROWS * D_DIM * 2;   // 4 MB
    __bf16* Xb = (__bf16*)(ws + off); off += (size_t)N_PTS  * D_DIM * 2;   // 8 MB
    float* rc   = (float*)(ws + off); off += (size_t)B_ROWS * 4;
    float* c2   = (float*)(ws + off); off += (size_t)N_PTS * 4;
    float* lsew = (float*)(ws + off); off += 256;
    float* pm   = (float*)(ws + off); off += (size_t)B_ROWS * NSPLIT * 4;
    float* ps   = (float*)(ws + off); off += (size_t)B_ROWS * NSPLIT * 4;

    const int prep_blocks = 1 + B_ROWS / 4 + N_PTS / 4;   // 6145
    prep_all_kernel<<<prep_blocks, 256, 0, stream>>>(x, X, W, xb, Xb, rc, c2, lsew);
    kde_gemm<<<dim3(B_ROWS / BM, NSPLIT), 256, 0, stream>>>(xb, Xb, c2, pm, ps);
    kde_combine<<<B_ROWS / 256, 256, 0, stream>>>(pm, ps, rc, lsew, out);
}